// Round 23
// baseline (291.816 us; speedup 1.0000x reference)
//
#include <hip/hip_runtime.h>
#include <hip/hip_bf16.h>
#include <hip/hip_fp8.h>

// Problem constants (fixed by setup_inputs): B=4096, d=128, M=8192, C=16
#define B_ROWS 4096
#define D_K    128
#define M_ROWS 8192
#define N_TOT  12288   // B_ROWS + M_ROWS
#define NCHUNK 32      // j-chunks (grid.x of sim), 384 cols each
#define JT_PER_CHUNK 6 // 6 tiles of 64 cols: 32*6*64 = 12288 = N_TOT (coverage!)
#define JCOLS  64      // cols per tile
#define NCLS   16

typedef __attribute__((ext_vector_type(4))) int   intx4;
typedef __attribute__((ext_vector_type(8))) int   intx8;
typedef __attribute__((ext_vector_type(4))) float floatx4;

__device__ __forceinline__ float fp8_to_f32(unsigned char b) {
    __hip_fp8_e4m3 h; h.__x = b; return float(h);
}

// ---------------------------------------------------------------------------
// Kernel 1 (R22 minus S/hist zeroing): normalize rows into fp8 G8
// (+log2e-scaled A8 for in-batch rows); emit selfdot[i] = ||g8_i||^2 and
// expself[i] = exp(selfdot[i]). One wave per row. Block 0 zeros out only.
// NO atomics anywhere.
// ---------------------------------------------------------------------------
__global__ __launch_bounds__(256) void nrm_kernel(
    const float* __restrict__ f, const float* __restrict__ fneg,
    unsigned char* __restrict__ G8, unsigned char* __restrict__ A8,
    float* __restrict__ selfdot, float* __restrict__ expself,
    float* __restrict__ out)
{
    const int tid  = threadIdx.x;
    const int wave = tid >> 6;
    const int lane = tid & 63;
    const int row  = blockIdx.x * 4 + wave;           // grid exact: 3072*4
    if (blockIdx.x == 0 && tid == 0) out[0] = 0.f;
    const float* src = (row < B_ROWS) ? (f + (size_t)row * D_K)
                                      : (fneg + (size_t)(row - B_ROWS) * D_K);
    float2 v = *reinterpret_cast<const float2*>(src + lane * 2);
    float ss = v.x * v.x + v.y * v.y;
    #pragma unroll
    for (int m = 1; m < 64; m <<= 1) ss += __shfl_xor(ss, m, 64);
    const float scale = 1.0f / fmaxf(sqrtf(ss), 1e-8f);   // 1/max(||x||, EPS)
    __hip_fp8_e4m3 q0(v.x * scale);
    __hip_fp8_e4m3 q1(v.y * scale);
    const unsigned short pk =
        (unsigned short)q0.__x | ((unsigned short)q1.__x << 8);
    *reinterpret_cast<unsigned short*>(G8 + (size_t)row * D_K + lane * 2) = pk;
    if (row < B_ROWS) {
        const float s2 = scale * 1.44269504f;             // * log2(e)
        __hip_fp8_e4m3 a0(v.x * s2);
        __hip_fp8_e4m3 a1(v.y * s2);
        const unsigned short pa =
            (unsigned short)a0.__x | ((unsigned short)a1.__x << 8);
        *reinterpret_cast<unsigned short*>(A8 + (size_t)row * D_K + lane * 2) = pa;
        // selfdot of the QUANTIZED row
        const float d0 = fp8_to_f32((unsigned char)(pk & 0xff));
        const float d1 = fp8_to_f32((unsigned char)(pk >> 8));
        float sd = d0 * d0 + d1 * d1;
        #pragma unroll
        for (int m = 1; m < 64; m <<= 1) sd += __shfl_xor(sd, m, 64);
        if (lane == 0) {
            selfdot[row] = sd;
            expself[row] = __expf(sd);
        }
    }
}

// ---------------------------------------------------------------------------
// Kernel 2 (R17 sim core, PURE): grid (32,32) = 1024 blocks. The csum
// service blocks (and their 2048 hist atomics onto one cache line + 65K S
// atomics — the suspected ~16us cross-XCD serialization tail) are GONE;
// their output is recomputed atomic-free in fin's class blocks.
// sim-block compute measured 13.8us (R21 NREP discriminator).
// ---------------------------------------------------------------------------
__global__ __launch_bounds__(256, 2) void sim_kernel(
    const unsigned char* __restrict__ G8, const unsigned char* __restrict__ A8,
    float* __restrict__ part_d)
{
    __shared__ unsigned char Bs[2][JCOLS * D_K];   // 2 x 8KB

    const int tid  = threadIdx.x;
    const int jc   = blockIdx.x;          // 0..31
    const int it   = blockIdx.y;          // 0..31
    const int wave = tid >> 6;            // 0..3 : i-quarter
    const int lane = tid & 63;
    const int i0   = it * 128 + wave * 32;

    const int r16 = lane & 15;
    const int grp = lane >> 4;            // 0..3

    // resident A fragments [a] from A8 (log2e-scaled): rows i0 + a*16 + r16
    const unsigned char* Abase = A8 + (size_t)(i0 + r16) * D_K + grp * 32;
    intx8 afr[2];
    #pragma unroll
    for (int a = 0; a < 2; ++a)
        afr[a] = *reinterpret_cast<const intx8*>(Abase + (size_t)a * 16 * D_K);

    float dsum[2][4];
    #pragma unroll
    for (int a = 0; a < 2; ++a)
        #pragma unroll
        for (int r = 0; r < 4; ++r) dsum[a][r] = 0.f;

    // staging: 8KB tile, 256 thr x 16B x 2 rounds. LDS linear byte
    // p = s*4096 + tid*16 -> row = s*32 + tid/8, slot = tid&7;
    // source granule pre-swizzled: gran = slot ^ ((row>>2)&1)
    int srcoff[2];
    #pragma unroll
    for (int s = 0; s < 2; ++s) {
        const int row  = s * 32 + (tid >> 3);
        const int gran = (tid & 7) ^ ((row >> 2) & 1);
        srcoff[s] = row * D_K + gran * 16;
    }

    intx4 streg[2];
    {   // prologue: load + write tile 0 into buf 0
        const unsigned char* src =
            G8 + (size_t)(jc * JT_PER_CHUNK) * JCOLS * D_K;
        #pragma unroll
        for (int s = 0; s < 2; ++s)
            streg[s] = *reinterpret_cast<const intx4*>(src + srcoff[s]);
        #pragma unroll
        for (int s = 0; s < 2; ++s)
            *reinterpret_cast<intx4*>(&Bs[0][0] + s * 4096 + tid * 16) =
                streg[s];
    }

    for (int t = 0; t < JT_PER_CHUNK; ++t) {
        const int cur = t & 1;
        __syncthreads();   // buf[cur] written & visible; buf[cur^1] reads done

        if (t + 1 < JT_PER_CHUNK) {
            const unsigned char* src =
                G8 + (size_t)(jc * JT_PER_CHUNK + t + 1) * JCOLS * D_K;
            #pragma unroll
            for (int s = 0; s < 2; ++s)
                streg[s] = *reinterpret_cast<const intx4*>(src + srcoff[s]);
        }

        floatx4 acc[2][4];
        #pragma unroll
        for (int a = 0; a < 2; ++a)
            #pragma unroll
            for (int b = 0; b < 4; ++b)
                acc[a][b] = (floatx4){0.f, 0.f, 0.f, 0.f};

        const unsigned char* base = &Bs[cur][0];
        #pragma unroll
        for (int b = 0; b < 4; ++b) {
            const int jloc = b * 16 + r16;
            const int sw   = (jloc >> 2) & 1;            // row bit 2
            intx4 lo = *reinterpret_cast<const intx4*>(
                base + jloc * D_K + ((2 * grp)     ^ sw) * 16);
            intx4 hi = *reinterpret_cast<const intx4*>(
                base + jloc * D_K + ((2 * grp + 1) ^ sw) * 16);
            intx8 bfr;
            if (sw) { intx4 tmp = lo; lo = hi; hi = tmp; }
            #pragma unroll
            for (int e = 0; e < 4; ++e) { bfr[e] = lo[e]; bfr[e + 4] = hi[e]; }
            #pragma unroll
            for (int a = 0; a < 2; ++a)
                acc[a][b] = __builtin_amdgcn_mfma_scale_f32_16x16x128_f8f6f4(
                    afr[a], bfr, acc[a][b], 0, 0,
                    0, 0x7F7F7F7F, 0, 0x7F7F7F7F);   // unity scales
        }

        // branch-free epilogue: acc = log2e*sim -> exp2 (native v_exp_f32)
        #pragma unroll
        for (int a = 0; a < 2; ++a)
            #pragma unroll
            for (int r = 0; r < 4; ++r) {
                float s0 = exp2f(acc[a][0][r]) + exp2f(acc[a][1][r]);
                float s1 = exp2f(acc[a][2][r]) + exp2f(acc[a][3][r]);
                dsum[a][r] += s0 + s1;
            }

        if (t + 1 < JT_PER_CHUNK) {
            #pragma unroll
            for (int s = 0; s < 2; ++s)
                *reinterpret_cast<intx4*>(
                    &Bs[cur ^ 1][0] + s * 4096 + tid * 16) = streg[s];
        }
    }

    // 16-lane (column-group) reduce
    #pragma unroll
    for (int a = 0; a < 2; ++a)
        #pragma unroll
        for (int r = 0; r < 4; ++r) {
            #pragma unroll
            for (int m = 1; m < 16; m <<= 1)
                dsum[a][r] += __shfl_xor(dsum[a][r], m, 64);
        }
    if (r16 == 0) {
        #pragma unroll
        for (int a = 0; a < 2; ++a)
            #pragma unroll
            for (int r = 0; r < 4; ++r)
                part_d[(size_t)(i0 + a * 16 + grp * 4 + r) * NCHUNK + jc] =
                    dsum[a][r];
    }
}

// ---------------------------------------------------------------------------
// Kernel 3 (atomic-free classes + R22 row part): grid 272 x 256.
// Blocks 0..255: row part (4 rows/wave):
//   denom_i = sum(part_d[i][*]) - expself[i]; lsum += log(denom_i).
// Blocks 256..271: class c = bid-256 scans all 4096 in-batch rows
//   (labels staged in LDS; unconditional coalesced G8 loads; PREDICATED
//   accumulate — no atomics): builds S_c (2 dims/lane), T_c, h; then
//   out -= ((<S_c,S_c> - T_c)/(h-1))/B.   [R22-verified algebra]
// Only atomics left: 272 single-address out-adds (measured cheap, R22).
// ---------------------------------------------------------------------------
__global__ __launch_bounds__(256) void fin_kernel(
    const unsigned char* __restrict__ G8, const float* __restrict__ part_d,
    const int* __restrict__ labels, const float* __restrict__ selfdot,
    const float* __restrict__ expself, float* __restrict__ out)
{
    const int tid  = threadIdx.x;
    const int wave = tid >> 6;
    const int lane = tid & 63;

    if (blockIdx.x >= 256) {       // ---- class blocks ----
        const int c = blockIdx.x - 256;
        __shared__ int   labs[B_ROWS];
        __shared__ float Sp[4][D_K];
        __shared__ float t4[4];
        __shared__ int   h4[4];
        for (int k = tid; k < B_ROWS; k += 256) labs[k] = labels[k];
        __syncthreads();

        float s0 = 0.f, s1 = 0.f, tc = 0.f;
        int   hc = 0;
        const int ibase = wave * 1024;
        #pragma unroll 4
        for (int itr = 0; itr < 1024; ++itr) {
            const int i = ibase + itr;
            const int match = (labs[i] == c) ? 1 : 0;
            const float fm = (float)match;
            const unsigned short pk = *reinterpret_cast<const unsigned short*>(
                G8 + (size_t)i * D_K + lane * 2);
            s0 += fm * fp8_to_f32((unsigned char)(pk & 0xff));
            s1 += fm * fp8_to_f32((unsigned char)(pk >> 8));
            if (lane == 0) { tc += fm * selfdot[i]; hc += match; }
        }
        Sp[wave][lane * 2]     = s0;
        Sp[wave][lane * 2 + 1] = s1;
        if (lane == 0) { t4[wave] = tc; h4[wave] = hc; }
        __syncthreads();

        if (wave == 0) {
            const float v0 = Sp[0][lane] + Sp[1][lane] + Sp[2][lane] + Sp[3][lane];
            const float v1 = Sp[0][lane + 64] + Sp[1][lane + 64]
                           + Sp[2][lane + 64] + Sp[3][lane + 64];
            float dsq = v0 * v0 + v1 * v1;
            #pragma unroll
            for (int m = 1; m < 64; m <<= 1) dsq += __shfl_xor(dsq, m, 64);
            if (lane == 0) {
                const float Tc = t4[0] + t4[1] + t4[2] + t4[3];
                const int   h  = h4[0] + h4[1] + h4[2] + h4[3];
                if (h > 1)
                    atomicAdd(out, -((dsq - Tc) / (float)(h - 1))
                                      * (1.0f / (float)B_ROWS));
            }
        }
        return;
    }

    // ---- row blocks: 256 blocks x 4 waves x 4 rows = 4096 rows ----
    __shared__ float w4[4];
    const int i0 = (blockIdx.x * 4 + wave) * 4;
    float pd[4];
    #pragma unroll
    for (int r = 0; r < 4; ++r)
        pd[r] = (lane < NCHUNK)
            ? part_d[(size_t)(i0 + r) * NCHUNK + lane] : 0.f;
    float es[4];
    #pragma unroll
    for (int r = 0; r < 4; ++r) es[r] = expself[i0 + r];

    #pragma unroll
    for (int r = 0; r < 4; ++r) {
        #pragma unroll
        for (int m = 1; m < 32; m <<= 1)
            pd[r] += __shfl_xor(pd[r], m, 64);
    }
    if (lane == 0) {
        float lsum = 0.f;
        #pragma unroll
        for (int r = 0; r < 4; ++r)
            lsum += __logf(pd[r] - es[r]);
        w4[wave] = lsum;
    }
    __syncthreads();
    if (tid == 0)
        atomicAdd(out, (w4[0] + w4[1] + w4[2] + w4[3]) * (1.0f / (float)B_ROWS));
}

// ---------------------------------------------------------------------------
extern "C" void kernel_launch(void* const* d_in, const int* in_sizes, int n_in,
                              void* d_out, int out_size, void* d_ws, size_t ws_size,
                              hipStream_t stream) {
    const float* f      = (const float*)d_in[0];
    const float* fneg   = (const float*)d_in[1];
    const int*   labels = (const int*)d_in[2];
    float*       out    = (float*)d_out;

    char* ws = (char*)d_ws;
    // Workspace layout (bytes):
    //   G8      : 12288*128  = 1,572,864   @ 0
    //   A8      : 4096*128   =   524,288   @ 1,572,864
    //   part_d  : 4096*32*4  =   524,288   @ 2,097,152
    //   selfdot : 4096*4     =    16,384   @ 2,621,440
    //   expself : 4096*4     =    16,384   @ 2,637,824
    unsigned char* G8      = (unsigned char*)(ws);
    unsigned char* A8      = (unsigned char*)(ws + 1572864);
    float*         part_d  = (float*)(ws + 2097152);
    float*         selfdot = (float*)(ws + 2621440);
    float*         expself = (float*)(ws + 2637824);

    nrm_kernel<<<N_TOT / 4, 256, 0, stream>>>(f, fneg, G8, A8, selfdot,
                                              expself, out);

    dim3 gridS(NCHUNK, 32);   // (32,32) = 1024 pure sim blocks
    sim_kernel<<<gridS, 256, 0, stream>>>(G8, A8, part_d);

    fin_kernel<<<272, 256, 0, stream>>>(G8, part_d, labels, selfdot,
                                        expself, out);
}

// Round 24
// 39.992 us; speedup vs baseline: 7.2968x; 7.2968x over previous
//
#include <hip/hip_runtime.h>
#include <hip/hip_bf16.h>
#include <hip/hip_fp8.h>

// Problem constants (fixed by setup_inputs): B=4096, d=128, M=8192, C=16
#define B_ROWS 4096
#define D_K    128
#define M_ROWS 8192
#define N_TOT  12288   // B_ROWS + M_ROWS
#define NCHUNK 32      // j-chunks (grid.x of sim), 384 cols each
#define JT_PER_CHUNK 6 // 6 tiles of 64 cols: 32*6*64 = 12288 = N_TOT (coverage!)
#define JCOLS  64      // cols per tile
#define NCLS   16
#define NSTRIPE 32     // csum row-stripes of 128

typedef __attribute__((ext_vector_type(4))) int   intx4;
typedef __attribute__((ext_vector_type(8))) int   intx8;
typedef __attribute__((ext_vector_type(4))) float floatx4;

__device__ __forceinline__ float fp8_to_f32(unsigned char b) {
    __hip_fp8_e4m3 h; h.__x = b; return float(h);
}

// ---------------------------------------------------------------------------
// Kernel 1 (R23-verbatim): normalize rows into fp8 G8 (+log2e-scaled A8 for
// in-batch rows); emit selfdot[i] = ||g8_i||^2, expself[i] = exp(selfdot).
// One wave per row. Block 0 zeros out. NO atomics.
// ---------------------------------------------------------------------------
__global__ __launch_bounds__(256) void nrm_kernel(
    const float* __restrict__ f, const float* __restrict__ fneg,
    unsigned char* __restrict__ G8, unsigned char* __restrict__ A8,
    float* __restrict__ selfdot, float* __restrict__ expself,
    float* __restrict__ out)
{
    const int tid  = threadIdx.x;
    const int wave = tid >> 6;
    const int lane = tid & 63;
    const int row  = blockIdx.x * 4 + wave;           // grid exact: 3072*4
    if (blockIdx.x == 0 && tid == 0) out[0] = 0.f;
    const float* src = (row < B_ROWS) ? (f + (size_t)row * D_K)
                                      : (fneg + (size_t)(row - B_ROWS) * D_K);
    float2 v = *reinterpret_cast<const float2*>(src + lane * 2);
    float ss = v.x * v.x + v.y * v.y;
    #pragma unroll
    for (int m = 1; m < 64; m <<= 1) ss += __shfl_xor(ss, m, 64);
    const float scale = 1.0f / fmaxf(sqrtf(ss), 1e-8f);   // 1/max(||x||, EPS)
    __hip_fp8_e4m3 q0(v.x * scale);
    __hip_fp8_e4m3 q1(v.y * scale);
    const unsigned short pk =
        (unsigned short)q0.__x | ((unsigned short)q1.__x << 8);
    *reinterpret_cast<unsigned short*>(G8 + (size_t)row * D_K + lane * 2) = pk;
    if (row < B_ROWS) {
        const float s2 = scale * 1.44269504f;             // * log2(e)
        __hip_fp8_e4m3 a0(v.x * s2);
        __hip_fp8_e4m3 a1(v.y * s2);
        const unsigned short pa =
            (unsigned short)a0.__x | ((unsigned short)a1.__x << 8);
        *reinterpret_cast<unsigned short*>(A8 + (size_t)row * D_K + lane * 2) = pa;
        const float d0 = fp8_to_f32((unsigned char)(pk & 0xff));
        const float d1 = fp8_to_f32((unsigned char)(pk >> 8));
        float sd = d0 * d0 + d1 * d1;
        #pragma unroll
        for (int m = 1; m < 64; m <<= 1) sd += __shfl_xor(sd, m, 64);
        if (lane == 0) {
            selfdot[row] = sd;
            expself[row] = __expf(sd);
        }
    }
}

// ---------------------------------------------------------------------------
// Kernel 2 (R17 sim core + ATOMIC-FREE csum svc): grid (32, 36).
//   y < 32 : sim (1024 blocks) — R17-verbatim, measured 13.8us (R21).
//   y >= 32: svc 0..127 = (stripe, dc) — SAME LDS-partial csum logic, but
//            the merge is now PLAIN STORES to partS[stripe][cls][128] and
//            partH[stripe][cls]. The ~20us cross-XCD atomic tail (R23
//            subtraction: 36.1 total vs 15.9 nrm+sim+gaps) is eliminated.
// ---------------------------------------------------------------------------
__global__ __launch_bounds__(256, 2) void sim_kernel(
    const unsigned char* __restrict__ G8, const unsigned char* __restrict__ A8,
    const int* __restrict__ labels, float* __restrict__ part_d,
    float* __restrict__ partS, int* __restrict__ partH)
{
    __shared__ unsigned char Bs[2][JCOLS * D_K];   // 2 x 8KB

    const int tid = threadIdx.x;

    if (blockIdx.y >= 32) {        // ---- csum svc blocks (plain-store merge) ----
        const int svc    = (blockIdx.y - 32) * NCHUNK + blockIdx.x;  // 0..127
        const int stripe = svc & 31;   // 128-row stripe
        const int dc     = svc >> 5;   // 0..3 : 32-dim chunk
        float* Sp = (float*)&Bs[0][0];
        int*   lh = (int*)(Sp + NCLS * 32);
        for (int k = tid; k < NCLS * 32; k += 256) Sp[k] = 0.f;
        if (tid < NCLS) lh[tid] = 0;
        __syncthreads();

        const int j0 = stripe * 128;
        if (dc == 0 && tid < 128) atomicAdd(&lh[labels[j0 + tid]], 1);  // LDS

        const int d = tid & 31;
        const int w = tid >> 5;               // 0..7 row-walkers
        for (int jj = w; jj < 128; jj += 8) {
            const int j = j0 + jj;
            const int c = labels[j];
            atomicAdd(&Sp[c * 32 + d],        // LDS atomic (block-local)
                      fp8_to_f32(G8[(size_t)j * D_K + dc * 32 + d]));
        }
        __syncthreads();
        for (int k = tid; k < NCLS * 32; k += 256) {
            const int c  = k >> 5;
            const int dd = k & 31;
            partS[((size_t)stripe * NCLS + c) * D_K + dc * 32 + dd] = Sp[k];
        }
        if (dc == 0 && tid < NCLS) partH[stripe * NCLS + tid] = lh[tid];
        return;
    }

    const int jc   = blockIdx.x;          // 0..31
    const int it   = blockIdx.y;          // 0..31
    const int wave = tid >> 6;            // 0..3 : i-quarter
    const int lane = tid & 63;
    const int i0   = it * 128 + wave * 32;

    const int r16 = lane & 15;
    const int grp = lane >> 4;            // 0..3

    // resident A fragments [a] from A8 (log2e-scaled): rows i0 + a*16 + r16
    const unsigned char* Abase = A8 + (size_t)(i0 + r16) * D_K + grp * 32;
    intx8 afr[2];
    #pragma unroll
    for (int a = 0; a < 2; ++a)
        afr[a] = *reinterpret_cast<const intx8*>(Abase + (size_t)a * 16 * D_K);

    float dsum[2][4];
    #pragma unroll
    for (int a = 0; a < 2; ++a)
        #pragma unroll
        for (int r = 0; r < 4; ++r) dsum[a][r] = 0.f;

    // staging: 8KB tile, 256 thr x 16B x 2 rounds. LDS linear byte
    // p = s*4096 + tid*16 -> row = s*32 + tid/8, slot = tid&7;
    // source granule pre-swizzled: gran = slot ^ ((row>>2)&1)
    int srcoff[2];
    #pragma unroll
    for (int s = 0; s < 2; ++s) {
        const int row  = s * 32 + (tid >> 3);
        const int gran = (tid & 7) ^ ((row >> 2) & 1);
        srcoff[s] = row * D_K + gran * 16;
    }

    intx4 streg[2];
    {   // prologue: load + write tile 0 into buf 0
        const unsigned char* src =
            G8 + (size_t)(jc * JT_PER_CHUNK) * JCOLS * D_K;
        #pragma unroll
        for (int s = 0; s < 2; ++s)
            streg[s] = *reinterpret_cast<const intx4*>(src + srcoff[s]);
        #pragma unroll
        for (int s = 0; s < 2; ++s)
            *reinterpret_cast<intx4*>(&Bs[0][0] + s * 4096 + tid * 16) =
                streg[s];
    }

    for (int t = 0; t < JT_PER_CHUNK; ++t) {
        const int cur = t & 1;
        __syncthreads();   // buf[cur] written & visible; buf[cur^1] reads done

        if (t + 1 < JT_PER_CHUNK) {
            const unsigned char* src =
                G8 + (size_t)(jc * JT_PER_CHUNK + t + 1) * JCOLS * D_K;
            #pragma unroll
            for (int s = 0; s < 2; ++s)
                streg[s] = *reinterpret_cast<const intx4*>(src + srcoff[s]);
        }

        floatx4 acc[2][4];
        #pragma unroll
        for (int a = 0; a < 2; ++a)
            #pragma unroll
            for (int b = 0; b < 4; ++b)
                acc[a][b] = (floatx4){0.f, 0.f, 0.f, 0.f};

        const unsigned char* base = &Bs[cur][0];
        #pragma unroll
        for (int b = 0; b < 4; ++b) {
            const int jloc = b * 16 + r16;
            const int sw   = (jloc >> 2) & 1;            // row bit 2
            intx4 lo = *reinterpret_cast<const intx4*>(
                base + jloc * D_K + ((2 * grp)     ^ sw) * 16);
            intx4 hi = *reinterpret_cast<const intx4*>(
                base + jloc * D_K + ((2 * grp + 1) ^ sw) * 16);
            intx8 bfr;
            if (sw) { intx4 tmp = lo; lo = hi; hi = tmp; }
            #pragma unroll
            for (int e = 0; e < 4; ++e) { bfr[e] = lo[e]; bfr[e + 4] = hi[e]; }
            #pragma unroll
            for (int a = 0; a < 2; ++a)
                acc[a][b] = __builtin_amdgcn_mfma_scale_f32_16x16x128_f8f6f4(
                    afr[a], bfr, acc[a][b], 0, 0,
                    0, 0x7F7F7F7F, 0, 0x7F7F7F7F);   // unity scales
        }

        // branch-free epilogue: acc = log2e*sim -> exp2 (native v_exp_f32)
        #pragma unroll
        for (int a = 0; a < 2; ++a)
            #pragma unroll
            for (int r = 0; r < 4; ++r) {
                float s0 = exp2f(acc[a][0][r]) + exp2f(acc[a][1][r]);
                float s1 = exp2f(acc[a][2][r]) + exp2f(acc[a][3][r]);
                dsum[a][r] += s0 + s1;
            }

        if (t + 1 < JT_PER_CHUNK) {
            #pragma unroll
            for (int s = 0; s < 2; ++s)
                *reinterpret_cast<intx4*>(
                    &Bs[cur ^ 1][0] + s * 4096 + tid * 16) = streg[s];
        }
    }

    // 16-lane (column-group) reduce
    #pragma unroll
    for (int a = 0; a < 2; ++a)
        #pragma unroll
        for (int r = 0; r < 4; ++r) {
            #pragma unroll
            for (int m = 1; m < 16; m <<= 1)
                dsum[a][r] += __shfl_xor(dsum[a][r], m, 64);
        }
    if (r16 == 0) {
        #pragma unroll
        for (int a = 0; a < 2; ++a)
            #pragma unroll
            for (int r = 0; r < 4; ++r)
                part_d[(size_t)(i0 + a * 16 + grp * 4 + r) * NCHUNK + jc] =
                    dsum[a][r];
    }
}

// ---------------------------------------------------------------------------
// Kernel 3: fin. Grid 272 x 256.
// Blocks 0..255 (row part, R23-verbatim — known fast): per wave 4 rows:
//   denom_i = sum(part_d[i][*]) - expself[i]; lsum += log(denom_i).
// Blocks 256..271 (class c): reduce partS over 32 stripes (32 independent
//   float2 loads/lane — full MLP), dsq = <S_c,S_c>; h from partH;
//   T_c = strided predicated scan of selfdot (16 iters/thread, R22-proven);
//   out -= ((dsq - T_c)/(h-1))/B.
// Only atomics: 272 single-address out-adds (measured cheap).
// ---------------------------------------------------------------------------
__global__ __launch_bounds__(256) void fin_kernel(
    const float* __restrict__ part_d, const float* __restrict__ partS,
    const int* __restrict__ partH, const int* __restrict__ labels,
    const float* __restrict__ selfdot, const float* __restrict__ expself,
    float* __restrict__ out)
{
    const int tid  = threadIdx.x;
    const int wave = tid >> 6;
    const int lane = tid & 63;

    if (blockIdx.x >= 256) {       // ---- class blocks ----
        const int c = blockIdx.x - 256;
        __shared__ float SpC[4][D_K];
        __shared__ float wt[4];

        // T_c: strided predicated scan (16 iters/thread)
        float tc = 0.f;
        for (int i = tid; i < B_ROWS; i += 256)
            tc += (labels[i] == c) ? selfdot[i] : 0.f;
        #pragma unroll
        for (int m = 1; m < 64; m <<= 1) tc += __shfl_xor(tc, m, 64);
        if (lane == 0) wt[wave] = tc;

        // S_c: each wave sums 8 stripes; dims 2/lane
        const int d0 = lane * 2;
        float s0 = 0.f, s1 = 0.f;
        for (int s = wave; s < NSTRIPE; s += 4) {
            float2 p = *reinterpret_cast<const float2*>(
                partS + ((size_t)s * NCLS + c) * D_K + d0);
            s0 += p.x; s1 += p.y;
        }
        SpC[wave][d0]     = s0;
        SpC[wave][d0 + 1] = s1;
        __syncthreads();

        if (wave == 0) {
            const float v0 = SpC[0][d0] + SpC[1][d0] + SpC[2][d0] + SpC[3][d0];
            const float v1 = SpC[0][d0 + 1] + SpC[1][d0 + 1]
                           + SpC[2][d0 + 1] + SpC[3][d0 + 1];
            float dsq = v0 * v0 + v1 * v1;
            // h: lanes 0..31 load partH[stripe][c]
            float hf = (lane < NSTRIPE)
                ? (float)partH[lane * NCLS + c] : 0.f;
            #pragma unroll
            for (int m = 1; m < 64; m <<= 1) {
                dsq += __shfl_xor(dsq, m, 64);
                hf  += __shfl_xor(hf, m, 64);
            }
            if (lane == 0) {
                const float Tc = wt[0] + wt[1] + wt[2] + wt[3];
                const int   h  = (int)hf;
                if (h > 1)
                    atomicAdd(out, -((dsq - Tc) / (float)(h - 1))
                                      * (1.0f / (float)B_ROWS));
            }
        }
        return;
    }

    // ---- row blocks: 256 blocks x 4 waves x 4 rows = 4096 rows ----
    __shared__ float w4[4];
    const int i0 = (blockIdx.x * 4 + wave) * 4;
    float pd[4];
    #pragma unroll
    for (int r = 0; r < 4; ++r)
        pd[r] = (lane < NCHUNK)
            ? part_d[(size_t)(i0 + r) * NCHUNK + lane] : 0.f;
    float es[4];
    #pragma unroll
    for (int r = 0; r < 4; ++r) es[r] = expself[i0 + r];

    #pragma unroll
    for (int r = 0; r < 4; ++r) {
        #pragma unroll
        for (int m = 1; m < 32; m <<= 1)
            pd[r] += __shfl_xor(pd[r], m, 64);
    }
    if (lane == 0) {
        float lsum = 0.f;
        #pragma unroll
        for (int r = 0; r < 4; ++r)
            lsum += __logf(pd[r] - es[r]);
        w4[wave] = lsum;
    }
    __syncthreads();
    if (tid == 0)
        atomicAdd(out, (w4[0] + w4[1] + w4[2] + w4[3]) * (1.0f / (float)B_ROWS));
}

// ---------------------------------------------------------------------------
extern "C" void kernel_launch(void* const* d_in, const int* in_sizes, int n_in,
                              void* d_out, int out_size, void* d_ws, size_t ws_size,
                              hipStream_t stream) {
    const float* f      = (const float*)d_in[0];
    const float* fneg   = (const float*)d_in[1];
    const int*   labels = (const int*)d_in[2];
    float*       out    = (float*)d_out;

    char* ws = (char*)d_ws;
    // Workspace layout (bytes):
    //   G8      : 12288*128      = 1,572,864   @ 0
    //   A8      : 4096*128       =   524,288   @ 1,572,864
    //   part_d  : 4096*32*4      =   524,288   @ 2,097,152
    //   partS   : 32*16*128*4    =   262,144   @ 2,621,440
    //   partH   : 32*16*4        =     2,048   @ 2,883,584
    //   selfdot : 4096*4         =    16,384   @ 2,885,632
    //   expself : 4096*4         =    16,384   @ 2,902,016
    unsigned char* G8      = (unsigned char*)(ws);
    unsigned char* A8      = (unsigned char*)(ws + 1572864);
    float*         part_d  = (float*)(ws + 2097152);
    float*         partS   = (float*)(ws + 2621440);
    int*           partH   = (int*)(ws + 2883584);
    float*         selfdot = (float*)(ws + 2885632);
    float*         expself = (float*)(ws + 2902016);

    nrm_kernel<<<N_TOT / 4, 256, 0, stream>>>(f, fneg, G8, A8, selfdot,
                                              expself, out);

    dim3 gridS(NCHUNK, 36);   // (32,36): 1024 sim blocks + 128 csum svc blocks
    sim_kernel<<<gridS, 256, 0, stream>>>(G8, A8, labels, part_d, partS, partH);

    fin_kernel<<<272, 256, 0, stream>>>(part_d, partS, partH, labels,
                                        selfdot, expself, out);
}